// Round 3
// baseline (755.913 us; speedup 1.0000x reference)
//
#include <hip/hip_runtime.h>
#include <hip/hip_fp16.h>

#define T_SEQ 256

typedef _Float16 half8 __attribute__((ext_vector_type(8)));
typedef float float4v __attribute__((ext_vector_type(4)));

__device__ __forceinline__ float fexp2(float x) { return __builtin_amdgcn_exp2f(x); }
__device__ __forceinline__ float frcp(float x) { return __builtin_amdgcn_rcpf(x); }
__device__ __forceinline__ float sigf(float x) { return frcp(1.f + fexp2(-1.4426950408889634f * x)); }
__device__ __forceinline__ float tanhf_(float x) { return 1.f - 2.f * frcp(1.f + fexp2(2.8853900817779268f * x)); }

// async global->LDS, 16B per lane; LDS dest = wave-uniform base + lane*16
__device__ __forceinline__ void gload_lds16(const void* g, void* l) {
    __builtin_amdgcn_global_load_lds((const __attribute__((address_space(1))) void*)g,
                                     (__attribute__((address_space(3))) void*)l, 16, 0, 0);
}

// Barrier that drains LDS ops only (stores/prefetch loads stay in flight).
__device__ __forceinline__ void relaxed_barrier() {
    __builtin_amdgcn_sched_barrier(0);
    asm volatile("s_waitcnt lgkmcnt(0)" ::: "memory");
    __builtin_amdgcn_s_barrier();
    asm volatile("" ::: "memory");
    __builtin_amdgcn_sched_barrier(0);
}
// l1 variant: also waits own global_load_lds (issued ~1 step earlier) so the
// LDS buffer it filled is globally visible after the barrier.
__device__ __forceinline__ void vm_barrier() {
    __builtin_amdgcn_sched_barrier(0);
    asm volatile("s_waitcnt vmcnt(0) lgkmcnt(0)" ::: "memory");
    __builtin_amdgcn_s_barrier();
    asm volatile("" ::: "memory");
    __builtin_amdgcn_sched_barrier(0);
}

// ---------------------------------------------------------------------------
// Layer-0. 32 WGs = 4 chains (n*2+d) x 8 batch-groups of 16 rows. 512 thr.
// Wave w owns gate tiles {w,w+8,w+16,w+24} -> i,f,g,o for h-cols [16w,16w+16).
// y0f slice (n,t,bg) = 8KB: [kk(8)][lane(64)][j(8)] fp16 (kk = d*4 + kk'),
// frag semantics: y[row=lane&15][c=kk*32+(lane>>4)*8+j].
// Writeback: coalesced b128 from the completed hfrag buffer, one step delayed.
// ---------------------------------------------------------------------------
__global__ __launch_bounds__(512, 1) void lstm_l0(
    const float* __restrict__ x, const float* __restrict__ h0,
    const float* __restrict__ c0, const float* __restrict__ wih0,
    const float* __restrict__ whh0, const float* __restrict__ b0,
    _Float16* __restrict__ y0f) {
    const int wg = blockIdx.x;
    const int chain = wg >> 3, n = chain >> 1, d = chain & 1;
    const int bg = wg & 7, bbase = bg * 16;
    const int tid = threadIdx.x;
    const int wave = tid >> 6, lane = tid & 63, lrow = lane & 15, lgrp = lane >> 4;

    __shared__ __align__(16) float xsT[T_SEQ][16];
    __shared__ __align__(16) _Float16 hfrag[2][4][64][8];

    {   // stage x transposed (once)
        int r = tid >> 5, ck = tid & 31;
        const float* xr = &x[((bbase + r) * 2 + n) * T_SEQ + ck * 8];
        float4v v0 = *(const float4v*)xr, v1 = *(const float4v*)(xr + 4);
#pragma unroll
        for (int i = 0; i < 4; ++i) { xsT[ck * 8 + i][r] = v0[i]; xsT[ck * 8 + 4 + i][r] = v1[i]; }
    }
    const int sidx = n * 4 + d;
    for (int idx = tid; idx < 256; idx += 512) {
        int kk = idx >> 6, l = idx & 63;
        int b = bbase + (l & 15), k0 = kk * 32 + (l >> 4) * 8;
        const float4v* s4 = (const float4v*)&h0[((size_t)(sidx * 128 + b)) * 128 + k0];
        float4v v0 = s4[0], v1 = s4[1];
        _Float16* dp = &hfrag[0][kk][l][0];
#pragma unroll
        for (int j = 0; j < 4; ++j) { dp[j] = (_Float16)v0[j]; dp[4 + j] = (_Float16)v1[j]; }
    }
    float wi[4], bi[4];
    half8 wf[4][4];
#pragma unroll
    for (int p = 0; p < 4; ++p) {
        int g = (wave + 8 * p) * 16 + lrow;
        wi[p] = wih0[chain * 512 + g];
        bi[p] = b0[chain * 512 + g];
        const float* sg = &whh0[(size_t)(chain * 512 + g) * 128];
#pragma unroll
        for (int kk = 0; kk < 4; ++kk) {
            const float4v* s4 = (const float4v*)&sg[kk * 32 + lgrp * 8];
            float4v v0 = s4[0], v1 = s4[1];
            half8 h;
#pragma unroll
            for (int j = 0; j < 4; ++j) { h[j] = (_Float16)v0[j]; h[4 + j] = (_Float16)v1[j]; }
            wf[p][kk] = h;
        }
    }
    const int hc = wave * 16 + lrow;
    float creg[4];
#pragma unroll
    for (int jj = 0; jj < 4; ++jj)
        creg[jj] = c0[((size_t)(sidx * 128 + bbase + 4 * lgrp + jj)) * 128 + hc];
    __syncthreads();

    const int kkw = hc >> 5, lsub = (hc >> 3) & 3, jd = hc & 7;

    for (int t = 0; t < T_SEQ; ++t) {
        const int cur = t & 1, nxt = cur ^ 1;
        const int tx = d ? (T_SEQ - 1 - t) : t;
        // compute-frag reads first (compiler hoists & issues all 4 together)
        half8 a[4];
#pragma unroll
        for (int kk = 0; kk < 4; ++kk) a[kk] = *(const half8*)&hfrag[cur][kk][lane][0];
        // coalesced writeback of previous step's h (hfrag[cur], fire-and-forget)
        if (t > 0 && tid < 256) {
            const int txp = d ? (T_SEQ - t) : (t - 1);
            half8 v = ((const half8*)&hfrag[cur][0][0][0])[tid];
            half8* dst = (half8*)&y0f[((size_t)(n * 256 + txp) * 8 + bg) * 4096 + d * 2048];
            dst[tid] = v;
        }
        float4v xv = *(const float4v*)&xsT[tx][4 * lgrp];
        float4v acc[4];
#pragma unroll
        for (int p = 0; p < 4; ++p) {
#pragma unroll
            for (int jj = 0; jj < 4; ++jj) acc[p][jj] = fmaf(xv[jj], wi[p], bi[p]);
        }
#pragma unroll
        for (int kk = 0; kk < 4; ++kk)
#pragma unroll
            for (int p = 0; p < 4; ++p)
                acc[p] = __builtin_amdgcn_mfma_f32_16x16x32_f16(a[kk], wf[p][kk], acc[p], 0, 0, 0);
#pragma unroll
        for (int jj = 0; jj < 4; ++jj) {
            float ig = sigf(acc[0][jj]), fg = sigf(acc[1][jj]);
            float gg = tanhf_(acc[2][jj]), og = sigf(acc[3][jj]);
            float c = fmaf(fg, creg[jj], ig * gg);
            creg[jj] = c;
            hfrag[nxt][kkw][16 * lsub + 4 * lgrp + jj][jd] = (_Float16)(og * tanhf_(c));
        }
        relaxed_barrier();
    }
    // final h (t=255) writeback: buffer nxt of t=255 is hfrag[0]
    if (tid < 256) {
        const int txl = d ? 0 : (T_SEQ - 1);
        half8 v = ((const half8*)&hfrag[0][0][0][0])[tid];
        half8* dst = (half8*)&y0f[((size_t)(n * 256 + txl) * 8 + bg) * 4096 + d * 2048];
        dst[tid] = v;
    }
}

// ---------------------------------------------------------------------------
// Layer-1. All weights resident (wih 128 + wf 64 regs, unified VGPR/AGPR).
// y slice prefetched one step ahead via global_load_lds (no VGPR cost, no
// reg->LDS pass); all 12 A-frag ds_reads issued up front each step.
// Backward dir needs only its first step (t=255 input).
// ---------------------------------------------------------------------------
__global__ __launch_bounds__(512, 1) void lstm_l1(
    const float* __restrict__ h0, const float* __restrict__ c0,
    const float* __restrict__ wih1, const float* __restrict__ whh1,
    const float* __restrict__ b1, const _Float16* __restrict__ y0f,
    float* __restrict__ lo) {
    const int wg = blockIdx.x;
    const int chain = wg >> 3, n = chain >> 1, d = chain & 1;
    const int bg = wg & 7, bbase = bg * 16;
    const int tid = threadIdx.x;
    const int wave = tid >> 6, lane = tid & 63, lrow = lane & 15, lgrp = lane >> 4;

    __shared__ __align__(16) _Float16 ybuf[2][4096];        // y A-frags, dbuf (16KB)
    __shared__ __align__(16) _Float16 hfrag[2][4][64][8];   // h A-frags, dbuf (8KB)

    const int sidx = n * 4 + 2 + d;
    for (int idx = tid; idx < 256; idx += 512) {
        int kk = idx >> 6, l = idx & 63;
        int b = bbase + (l & 15), k0 = kk * 32 + (l >> 4) * 8;
        const float4v* s4 = (const float4v*)&h0[((size_t)(sidx * 128 + b)) * 128 + k0];
        float4v v0 = s4[0], v1 = s4[1];
        _Float16* dp = &hfrag[0][kk][l][0];
#pragma unroll
        for (int j = 0; j < 4; ++j) { dp[j] = (_Float16)v0[j]; dp[4 + j] = (_Float16)v1[j]; }
    }
    float bi[4];
    half8 wih[4][8];   // 128 regs
    half8 wf[4][4];    // 64 regs
#pragma unroll
    for (int p = 0; p < 4; ++p) {
        int g = (wave + 8 * p) * 16 + lrow;
        bi[p] = b1[chain * 512 + g];
        const float* sg = &wih1[(size_t)(chain * 512 + g) * 256];
#pragma unroll
        for (int kk = 0; kk < 8; ++kk) {
            const float4v* s4 = (const float4v*)&sg[kk * 32 + lgrp * 8];
            float4v v0 = s4[0], v1 = s4[1];
            half8 h;
#pragma unroll
            for (int j = 0; j < 4; ++j) { h[j] = (_Float16)v0[j]; h[4 + j] = (_Float16)v1[j]; }
            wih[p][kk] = h;
        }
        const float* sh = &whh1[(size_t)(chain * 512 + g) * 128];
#pragma unroll
        for (int kk = 0; kk < 4; ++kk) {
            const float4v* s4 = (const float4v*)&sh[kk * 32 + lgrp * 8];
            float4v v0 = s4[0], v1 = s4[1];
            half8 h;
#pragma unroll
            for (int j = 0; j < 4; ++j) { h[j] = (_Float16)v0[j]; h[4 + j] = (_Float16)v1[j]; }
            wf[p][kk] = h;
        }
    }
    const int hc = wave * 16 + lrow;
    float creg[4];
#pragma unroll
    for (int jj = 0; jj < 4; ++jj)
        creg[jj] = c0[((size_t)(sidx * 128 + bbase + 4 * lgrp + jj)) * 128 + hc];

    const int nsteps = d ? 1 : T_SEQ;
    const int t0 = d ? (T_SEQ - 1) : 0;
    // stage y(t0): async copy, frag-order-linear on both sides
    gload_lds16(&y0f[(((size_t)n * 256 + t0) * 8 + bg) * 4096 + (size_t)tid * 8],
                &ybuf[0][wave * 512]);
    asm volatile("s_waitcnt vmcnt(0)" ::: "memory");
    __syncthreads();

    const int kkw = hc >> 5, lsub = (hc >> 3) & 3, jd = hc & 7;

    for (int t = 0; t < nsteps; ++t) {
        const int cur = t & 1, nxt = cur ^ 1;
        if (t + 1 < nsteps)  // prefetch next y slice straight into LDS
            gload_lds16(&y0f[(((size_t)n * 256 + (t + 1)) * 8 + bg) * 4096 + (size_t)tid * 8],
                        &ybuf[nxt][wave * 512]);
        // all A-frags issued up front (compiler schedules the 12 ds_read_b128)
        half8 ay[8], ah[4];
#pragma unroll
        for (int kk = 0; kk < 8; ++kk) ay[kk] = *(const half8*)&ybuf[cur][kk * 512 + lane * 8];
#pragma unroll
        for (int kk = 0; kk < 4; ++kk) ah[kk] = *(const half8*)&hfrag[cur][kk][lane][0];
        float4v acc[4];
#pragma unroll
        for (int p = 0; p < 4; ++p) acc[p] = (float4v){bi[p], bi[p], bi[p], bi[p]};
#pragma unroll
        for (int kk = 0; kk < 8; ++kk)
#pragma unroll
            for (int p = 0; p < 4; ++p)
                acc[p] = __builtin_amdgcn_mfma_f32_16x16x32_f16(ay[kk], wih[p][kk], acc[p], 0, 0, 0);
#pragma unroll
        for (int kk = 0; kk < 4; ++kk)
#pragma unroll
            for (int p = 0; p < 4; ++p)
                acc[p] = __builtin_amdgcn_mfma_f32_16x16x32_f16(ah[kk], wf[p][kk], acc[p], 0, 0, 0);
        float hout[4];
#pragma unroll
        for (int jj = 0; jj < 4; ++jj) {
            float ig = sigf(acc[0][jj]), fg = sigf(acc[1][jj]);
            float gg = tanhf_(acc[2][jj]), og = sigf(acc[3][jj]);
            float c = fmaf(fg, creg[jj], ig * gg);
            creg[jj] = c;
            hout[jj] = og * tanhf_(c);
        }
#pragma unroll
        for (int jj = 0; jj < 4; ++jj)
            hfrag[nxt][kkw][16 * lsub + 4 * lgrp + jj][jd] = (_Float16)hout[jj];
        if (t == nsteps - 1) {
#pragma unroll
            for (int jj = 0; jj < 4; ++jj)
                lo[(size_t)(bbase + 4 * lgrp + jj) * 512 + n * 256 + d * 128 + hc] = hout[jj];
        }
        vm_barrier();  // drains own gload_lds (issued ~1 step ago) + LDS writes
    }
}

// ---------------------------------------------------------------------------
// FC head: fc0(512->256) -> relu(t+LN(t)) -> fc1(256->256) -> relu(t+LN(t))
// -> fc2(256->64). One WG per batch row, 256 threads.
// ---------------------------------------------------------------------------
__global__ __launch_bounds__(256) void head_k(
    const float* __restrict__ lo,
    const float* __restrict__ w0, const float* __restrict__ bb0,
    const float* __restrict__ a0, const float* __restrict__ g0,
    const float* __restrict__ w1, const float* __restrict__ bb1,
    const float* __restrict__ a1, const float* __restrict__ g1,
    const float* __restrict__ w2, const float* __restrict__ bb2,
    float* __restrict__ out) {
    const int b = blockIdx.x, j = threadIdx.x;
    const int lane = j & 63, wid = j >> 6;
    __shared__ float row[512];
    __shared__ float buf[256];
    __shared__ float redA[4], redB[4];

    row[j] = lo[b * 512 + j];
    row[256 + j] = lo[b * 512 + 256 + j];
    __syncthreads();

    float s = bb0[j];
#pragma unroll 8
    for (int k = 0; k < 512; ++k) s = fmaf(row[k], w0[k * 256 + j], s);
    float v = s, v2 = s * s;
#pragma unroll
    for (int off = 32; off; off >>= 1) { v += __shfl_xor(v, off); v2 += __shfl_xor(v2, off); }
    if (lane == 0) { redA[wid] = v; redB[wid] = v2; }
    __syncthreads();
    float S = redA[0] + redA[1] + redA[2] + redA[3];
    float SS = redB[0] + redB[1] + redB[2] + redB[3];
    float mu = S * (1.f / 256.f);
    float var = (SS - S * mu) * (1.f / 255.f);
    float stdv = sqrtf(var) + 1e-6f;
    float t0 = fmaxf(s + (s - mu) / stdv * a0[j] + g0[j], 0.f);
    buf[j] = t0;
    __syncthreads();

    float s1 = bb1[j];
#pragma unroll 8
    for (int k = 0; k < 256; ++k) s1 = fmaf(buf[k], w1[k * 256 + j], s1);
    v = s1; v2 = s1 * s1;
#pragma unroll
    for (int off = 32; off; off >>= 1) { v += __shfl_xor(v, off); v2 += __shfl_xor(v2, off); }
    if (lane == 0) { redA[wid] = v; redB[wid] = v2; }
    __syncthreads();
    S = redA[0] + redA[1] + redA[2] + redA[3];
    SS = redB[0] + redB[1] + redB[2] + redB[3];
    mu = S * (1.f / 256.f);
    var = (SS - S * mu) * (1.f / 255.f);
    stdv = sqrtf(var) + 1e-6f;
    float t1 = fmaxf(s1 + (s1 - mu) / stdv * a1[j] + g1[j], 0.f);
    __syncthreads();
    buf[j] = t1;
    __syncthreads();

    if (j < 64) {
        float s2 = bb2[j];
#pragma unroll 8
        for (int k = 0; k < 256; ++k) s2 = fmaf(buf[k], w2[k * 64 + j], s2);
        out[b * 64 + j] = s2;
    }
}

extern "C" void kernel_launch(void* const* d_in, const int* in_sizes, int n_in,
                              void* d_out, int out_size, void* d_ws, size_t ws_size,
                              hipStream_t stream) {
    const float* x    = (const float*)d_in[0];
    const float* h0   = (const float*)d_in[1];
    const float* c0   = (const float*)d_in[2];
    const float* wih0 = (const float*)d_in[3];
    const float* whh0 = (const float*)d_in[4];
    const float* bb0  = (const float*)d_in[5];
    const float* wih1 = (const float*)d_in[6];
    const float* whh1 = (const float*)d_in[7];
    const float* bb1  = (const float*)d_in[8];
    const float* wfc0 = (const float*)d_in[9];
    const float* bfc0 = (const float*)d_in[10];
    const float* ln0a = (const float*)d_in[11];
    const float* ln0b = (const float*)d_in[12];
    const float* wfc1 = (const float*)d_in[13];
    const float* bfc1 = (const float*)d_in[14];
    const float* ln1a = (const float*)d_in[15];
    const float* ln1b = (const float*)d_in[16];
    const float* wfc2 = (const float*)d_in[17];
    const float* bfc2 = (const float*)d_in[18];

    // workspace: y0f fp16 [2][256][8][8][64][8] = 32 MiB; lo fp32 [128][512]
    char* ws = (char*)d_ws;
    _Float16* y0f = (_Float16*)ws;
    float*    lo  = (float*)(ws + (size_t)33554432);

    lstm_l0<<<dim3(32), dim3(512), 0, stream>>>(x, h0, c0, wih0, whh0, bb0, y0f);
    lstm_l1<<<dim3(32), dim3(512), 0, stream>>>(h0, c0, wih1, whh1, bb1, y0f, lo);
    head_k<<<dim3(128), dim3(256), 0, stream>>>(lo, wfc0, bfc0, ln0a, ln0b,
                                                wfc1, bfc1, ln1a, ln1b, wfc2, bfc2,
                                                (float*)d_out);
}